// Round 7
// baseline (587.283 us; speedup 1.0000x reference)
//
#include <hip/hip_runtime.h>
#include <math.h>

#pragma clang fp contract(off)

typedef unsigned int u32;

#define N_NEUR 262144                 // 32*8192 neurons
#define TT     128                    // time steps
#define OB     ((size_t)N_NEUR * TT)  // floats in spike region of out
#define PB     128                    // persistent blocks (<= 256 CUs -> co-resident)
#define PT     512                    // threads/block (8 waves)
#define NW     8
#define GUARD_MAX (1 << 14)           // bounded spin: terminate, never hang

__device__ __forceinline__ float f4c(const float4 v, int c) {
  switch (c & 3) { case 0: return v.x; case 1: return v.y; case 2: return v.z; default: return v.w; }
}
__device__ __forceinline__ float wredf(float v) {
#pragma unroll
  for (int o = 32; o; o >>= 1) v += __shfl_xor(v, o);
  return v;
}
__device__ __forceinline__ int wredi(int v) {
#pragma unroll
  for (int o = 32; o; o >>= 1) v += __shfl_xor(v, o);
  return v;
}

__launch_bounds__(PT)
__global__ void snn_persist(const float* __restrict__ in, const float* __restrict__ tsp,
                            const float* __restrict__ abp, float* __restrict__ out,
                            u32* __restrict__ bits2, u32* __restrict__ g_cnt,
                            float* __restrict__ wm, float* __restrict__ wt,
                            float* __restrict__ wa)
{
#pragma clang fp contract(off)
  const int tid  = threadIdx.x;
  const int bid  = blockIdx.x;
  const int gtid = bid * PT + tid;          // 0..65535, 4 neurons each
  const int lane = tid & 63;
  const int wv   = tid >> 6;

  // Verified-exact constants (R6, absmax 0.0): CR expf of the f32 quotients.
  const float alp = __uint_as_float(0x3F7383C5u);
  const float bet = __uint_as_float(0x3F519856u);
  const float gma = __uint_as_float(0x3F7D73E8u);
  const float omg = 1.0f - gma;
  const float tsv = tsp[0];
  const float abv = abp[0];

  float s0=0.f,s1=0.f,s2=0.f,s3=0.f;
  float m0=0.f,m1=0.f,m2=0.f,m3=0.f;
  float a0=0.f,a1=0.f,a2=0.f,a3=0.f;
  float ema = 0.f;
  float sc  = (tsv + 0.1f * fmaxf(ema - 0.01f, 0.0f)) + abv;

  __shared__ float shm[NW], sht[NW];
  __shared__ int   shc[NW];
  __shared__ u32   s_tot;

  const int n0 = gtid * 4;
  const float* r0 = in + (size_t)(n0 + 0) * TT;
  const float* r1 = in + (size_t)(n0 + 1) * TT;
  const float* r2 = in + (size_t)(n0 + 2) * TT;
  const float* r3 = in + (size_t)(n0 + 3) * TT;

  // One step: neuron math (byte-identical to R6) + block reduce + grid
  // publish/poll of the integer spike count + ema/sc update.
#define STEPSYNC(I0, I1, I2, I3, T_) {                                         \
    s0 = __builtin_fmaf(bet, s0, (I0));                                        \
    m0 = __builtin_fmaf(alp, m0, s0);                                          \
    const float aw0 = omg * m0;                                                \
    a0 = __builtin_fmaf(gma, a0, aw0);                                         \
    const float th0 = __builtin_fmaf(0.1f, a0, sc);                            \
    const bool sp0 = (m0 >= th0); if (sp0) m0 = m0 - th0;                      \
    s1 = __builtin_fmaf(bet, s1, (I1));                                        \
    m1 = __builtin_fmaf(alp, m1, s1);                                          \
    const float aw1 = omg * m1;                                                \
    a1 = __builtin_fmaf(gma, a1, aw1);                                         \
    const float th1 = __builtin_fmaf(0.1f, a1, sc);                            \
    const bool sp1 = (m1 >= th1); if (sp1) m1 = m1 - th1;                      \
    s2 = __builtin_fmaf(bet, s2, (I2));                                        \
    m2 = __builtin_fmaf(alp, m2, s2);                                          \
    const float aw2 = omg * m2;                                                \
    a2 = __builtin_fmaf(gma, a2, aw2);                                         \
    const float th2 = __builtin_fmaf(0.1f, a2, sc);                            \
    const bool sp2 = (m2 >= th2); if (sp2) m2 = m2 - th2;                      \
    s3 = __builtin_fmaf(bet, s3, (I3));                                        \
    m3 = __builtin_fmaf(alp, m3, s3);                                          \
    const float aw3 = omg * m3;                                                \
    a3 = __builtin_fmaf(gma, a3, aw3);                                         \
    const float th3 = __builtin_fmaf(0.1f, a3, sc);                            \
    const bool sp3 = (m3 >= th3); if (sp3) m3 = m3 - th3;                      \
    u32 nib = (u32)sp0 | ((u32)sp1 << 1) | ((u32)sp2 << 2) | ((u32)sp3 << 3);  \
    u32 word = nib << (4 * (tid & 7));                                         \
    word |= (u32)__shfl_xor((int)word, 1);                                     \
    word |= (u32)__shfl_xor((int)word, 2);                                     \
    word |= (u32)__shfl_xor((int)word, 4);                                     \
    if ((tid & 7) == 0) bits2[(size_t)(gtid >> 3) * TT + (T_)] = word;         \
    float msum = ((m0 + m1) + m2) + m3;                                        \
    float tsum = ((th0 + th1) + th2) + th3;                                    \
    int   cnt  = (int)sp0 + (int)sp1 + (int)sp2 + (int)sp3;                    \
    msum = wredf(msum); tsum = wredf(tsum); cnt = wredi(cnt);                  \
    if (lane == 0) { shm[wv] = msum; sht[wv] = tsum; shc[wv] = cnt; }          \
    __syncthreads();                                                           \
    if (wv == 0) {                                                             \
      if (lane == 0) {                                                         \
        float bm = 0.f, bt = 0.f; int bc = 0;                                  \
        for (int w = 0; w < NW; ++w) { bm += shm[w]; bt += sht[w]; bc += shc[w]; } \
        wm[(size_t)(T_) * PB + bid] = bm;                                      \
        wt[(size_t)(T_) * PB + bid] = bt;                                      \
        __hip_atomic_store(&g_cnt[(size_t)(T_) * PB + bid], (u32)bc + 1u,      \
                           __ATOMIC_RELAXED, __HIP_MEMORY_SCOPE_AGENT);        \
      }                                                                        \
      const u32* slots_ = g_cnt + (size_t)(T_) * PB;                           \
      u32 v0_, v1_; int gd_ = 0;                                               \
      while (1) {                                                              \
        v0_ = __hip_atomic_load(&slots_[lane],      __ATOMIC_RELAXED, __HIP_MEMORY_SCOPE_AGENT); \
        v1_ = __hip_atomic_load(&slots_[lane + 64], __ATOMIC_RELAXED, __HIP_MEMORY_SCOPE_AGENT); \
        if (__all(v0_ != 0u && v1_ != 0u)) break;                              \
        if (++gd_ > GUARD_MAX) break;                                          \
        __builtin_amdgcn_s_sleep(1);                                           \
      }                                                                        \
      int ss_ = (int)(v0_ ? v0_ - 1u : 0u) + (int)(v1_ ? v1_ - 1u : 0u);       \
      ss_ = wredi(ss_);                                                        \
      if (lane == 0) s_tot = (u32)ss_;                                         \
    }                                                                          \
    __syncthreads();                                                           \
    const float mean_ = (float)s_tot * 3.814697265625e-06f;                    \
    ema = __builtin_fmaf(0.99f, ema, 0.01f * mean_);                           \
    sc  = (tsv + 0.1f * fmaxf(ema - 0.01f, 0.0f)) + abv;                       \
  }

#define LOADC(X0,X1,X2,X3,X4,X5,X6,X7, c) {            \
    X0 = *(const float4*)(r0 + (c) * 8);               \
    X1 = *(const float4*)(r0 + (c) * 8 + 4);           \
    X2 = *(const float4*)(r1 + (c) * 8);               \
    X3 = *(const float4*)(r1 + (c) * 8 + 4);           \
    X4 = *(const float4*)(r2 + (c) * 8);               \
    X5 = *(const float4*)(r2 + (c) * 8 + 4);           \
    X6 = *(const float4*)(r3 + (c) * 8);               \
    X7 = *(const float4*)(r3 + (c) * 8 + 4); }

#define DOCHUNK(X0,X1,X2,X3,X4,X5,X6,X7, c) {                     \
    _Pragma("unroll")                                             \
    for (int k = 0; k < 8; ++k) {                                 \
      const float i0_ = (k < 4) ? f4c(X0, k) : f4c(X1, k);        \
      const float i1_ = (k < 4) ? f4c(X2, k) : f4c(X3, k);        \
      const float i2_ = (k < 4) ? f4c(X4, k) : f4c(X5, k);        \
      const float i3_ = (k < 4) ? f4c(X6, k) : f4c(X7, k);        \
      STEPSYNC(i0_, i1_, i2_, i3_, (c) * 8 + k);                  \
    } }

  float4 A0,A1,A2,A3,A4,A5,A6,A7;
  float4 B0,B1,B2,B3,B4,B5,B6,B7;

  LOADC(A0,A1,A2,A3,A4,A5,A6,A7, 0);
  for (int cc = 0; cc < 8; ++cc) {
    LOADC(B0,B1,B2,B3,B4,B5,B6,B7, 2 * cc + 1);         // prefetch odd chunk
    DOCHUNK(A0,A1,A2,A3,A4,A5,A6,A7, 2 * cc);
    if (cc < 7) LOADC(A0,A1,A2,A3,A4,A5,A6,A7, 2 * cc + 2);  // prefetch next even
    DOCHUNK(B0,B1,B2,B3,B4,B5,B6,B7, 2 * cc + 1);
  }
#undef DOCHUNK
#undef LOADC
#undef STEPSYNC

  // final adaptation partial + final ema
  float asum = ((a0 + a1) + a2) + a3;
  asum = wredf(asum);
  if (lane == 0) shm[wv] = asum;
  __syncthreads();
  if (tid == 0) {
    float bs = 0.f;
    for (int w = 0; w < NW; ++w) bs += shm[w];
    wa[bid] = bs;
    if (bid == 0) out[OB + 256] = ema;   // ema after step 127
  }
}

// Deterministic fold of per-block trace partials (all 128 steps) + adaptation.
__launch_bounds__(256)
__global__ void snn_finish(const float* __restrict__ wm, const float* __restrict__ wt,
                           const float* __restrict__ wa, float* __restrict__ out)
{
#pragma clang fp contract(off)
  const int tid = threadIdx.x;
  const float inv = 3.814697265625e-06f;   // 2^-18
  if (tid < 128) {
    float s = 0.f;
    for (int b = 0; b < PB; ++b) s += wm[(size_t)tid * PB + b];
    out[OB + tid] = s * inv;
  } else {
    const int t = tid - 128;
    float s = 0.f;
    for (int b = 0; b < PB; ++b) s += wt[(size_t)t * PB + b];
    out[OB + 128 + t] = s * inv;
  }
  if (tid == 0) {
    float s = 0.f;
    for (int b = 0; b < PB; ++b) s += wa[b];
    out[OB + 257] = s * inv;
  }
}

// bits2[word][t] -> float spikes [n][t]; uint4 reads + float4 writes, coalesced.
__global__ void snn_expand(const u32* __restrict__ bits2, float* __restrict__ outF)
{
  const int gtid = blockIdx.x * blockDim.x + threadIdx.x;
  const int wave = gtid >> 6, lane = gtid & 63;
  const int nwaves = (gridDim.x * blockDim.x) >> 6;
  const int nloc = lane >> 5;     // which neuron of the pair
  const int tq   = lane & 31;     // float4 chunk over t
  for (int pair = wave; pair < N_NEUR / 2; pair += nwaves) {
    const int n = 2 * pair + nloc;
    const uint4 w = *(const uint4*)(bits2 + (size_t)(n >> 5) * TT + 4 * tq);
    const int b = n & 31;
    float4 f;
    f.x = (float)((w.x >> b) & 1u);
    f.y = (float)((w.y >> b) & 1u);
    f.z = (float)((w.z >> b) & 1u);
    f.w = (float)((w.w >> b) & 1u);
    ((float4*)outF)[(size_t)n * (TT / 4) + tq] = f;
  }
}

extern "C" void kernel_launch(void* const* d_in, const int* in_sizes, int n_in,
                              void* d_out, int out_size, void* d_ws, size_t ws_size,
                              hipStream_t stream)
{
  const float* in  = (const float*)d_in[0];
  const float* tsp = (const float*)d_in[1];
  const float* abp = (const float*)d_in[2];
  float* out = (float*)d_out;
  unsigned char* ws = (unsigned char*)d_ws;

  if (ws_size < 4500000u) return;   // need ~4.4 MiB scratch

  u32*   bits2 = (u32*)(ws);                    // 4 MiB  [8192 words][128 t]
  u32*   g_cnt = (u32*)(ws + 4194304);          // 64 KiB [128 t][128 b] count+1 slots
  float* wm    = (float*)(ws + 4259840);        // 64 KiB [128 t][128 b]
  float* wt    = (float*)(ws + 4325376);        // 64 KiB
  float* wa    = (float*)(ws + 4390912);        // 512 B

  hipMemsetAsync(g_cnt, 0, 65536, stream);      // zero ready-flag slots (in-graph)

  snn_persist<<<dim3(PB), dim3(PT), 0, stream>>>(in, tsp, abp, out,
                                                 bits2, g_cnt, wm, wt, wa);
  snn_finish<<<dim3(1), dim3(256), 0, stream>>>(wm, wt, wa, out);
  snn_expand<<<dim3(2048), dim3(256), 0, stream>>>(bits2, out);
}

// Round 8
// 392.116 us; speedup vs baseline: 1.4977x; 1.4977x over previous
//
#include <hip/hip_runtime.h>
#include <math.h>

#pragma clang fp contract(off)

typedef unsigned int u32;

#define N_NEUR 262144                 // 32*8192 neurons
#define TT     128                    // time steps
#define OB     ((size_t)N_NEUR * TT)  // floats in spike region of out
#define PB     128                    // persistent blocks (<= 256 CUs -> co-resident)
#define PT     512                    // threads/block (8 waves)
#define NW     8
#define GUARD_MAX (1 << 16)           // bounded spin: terminate, never hang

__device__ __forceinline__ float f4c(const float4 v, int c) {
  switch (c & 3) { case 0: return v.x; case 1: return v.y; case 2: return v.z; default: return v.w; }
}
__device__ __forceinline__ float wredf(float v) {
#pragma unroll
  for (int o = 32; o; o >>= 1) v += __shfl_xor(v, o);
  return v;
}
__device__ __forceinline__ int wredi(int v) {
#pragma unroll
  for (int o = 32; o; o >>= 1) v += __shfl_xor(v, o);
  return v;
}

__launch_bounds__(PT)
__global__ void snn_persist(const float* __restrict__ in, const float* __restrict__ tsp,
                            const float* __restrict__ abp, float* __restrict__ out,
                            u32* __restrict__ bits2, u32* __restrict__ g_cnt,
                            u32* __restrict__ g_tot, float* __restrict__ wm,
                            float* __restrict__ wt, float* __restrict__ wa)
{
#pragma clang fp contract(off)
  const int tid  = threadIdx.x;
  const int bid  = blockIdx.x;
  const int gtid = bid * PT + tid;          // 0..65535, 4 neurons each
  const int lane = tid & 63;
  const int wv   = tid >> 6;

  // Verified-exact constants (R6/R7, absmax 0.0): CR expf of the f32 quotients.
  const float alp = __uint_as_float(0x3F7383C5u);
  const float bet = __uint_as_float(0x3F519856u);
  const float gma = __uint_as_float(0x3F7D73E8u);
  const float omg = 1.0f - gma;
  const float tsv = tsp[0];
  const float abv = abp[0];

  float s0=0.f,s1=0.f,s2=0.f,s3=0.f;
  float m0=0.f,m1=0.f,m2=0.f,m3=0.f;
  float a0=0.f,a1=0.f,a2=0.f,a3=0.f;
  float ema = 0.f;
  float sc  = (tsv + 0.1f * fmaxf(ema - 0.01f, 0.0f)) + abv;

  __shared__ int   shc[NW];
  __shared__ float shm[NW];
  __shared__ u32   s_tot;

  const int n0 = gtid * 4;
  const float* r0 = in + (size_t)(n0 + 0) * TT;
  const float* r1 = in + (size_t)(n0 + 1) * TT;
  const float* r2 = in + (size_t)(n0 + 2) * TT;
  const float* r3 = in + (size_t)(n0 + 3) * TT;

  // One step: neuron math (byte-identical to R6/R7) + count publish +
  // master-collect/broadcast + (trace work hidden under the round trip).
#define STEPSYNC(I0, I1, I2, I3, T_) {                                         \
    s0 = __builtin_fmaf(bet, s0, (I0));                                        \
    m0 = __builtin_fmaf(alp, m0, s0);                                          \
    const float aw0 = omg * m0;                                                \
    a0 = __builtin_fmaf(gma, a0, aw0);                                         \
    const float th0 = __builtin_fmaf(0.1f, a0, sc);                            \
    const bool sp0 = (m0 >= th0); if (sp0) m0 = m0 - th0;                      \
    s1 = __builtin_fmaf(bet, s1, (I1));                                        \
    m1 = __builtin_fmaf(alp, m1, s1);                                          \
    const float aw1 = omg * m1;                                                \
    a1 = __builtin_fmaf(gma, a1, aw1);                                         \
    const float th1 = __builtin_fmaf(0.1f, a1, sc);                            \
    const bool sp1 = (m1 >= th1); if (sp1) m1 = m1 - th1;                      \
    s2 = __builtin_fmaf(bet, s2, (I2));                                        \
    m2 = __builtin_fmaf(alp, m2, s2);                                          \
    const float aw2 = omg * m2;                                                \
    a2 = __builtin_fmaf(gma, a2, aw2);                                         \
    const float th2 = __builtin_fmaf(0.1f, a2, sc);                            \
    const bool sp2 = (m2 >= th2); if (sp2) m2 = m2 - th2;                      \
    s3 = __builtin_fmaf(bet, s3, (I3));                                        \
    m3 = __builtin_fmaf(alp, m3, s3);                                          \
    const float aw3 = omg * m3;                                                \
    a3 = __builtin_fmaf(gma, a3, aw3);                                         \
    const float th3 = __builtin_fmaf(0.1f, a3, sc);                            \
    const bool sp3 = (m3 >= th3); if (sp3) m3 = m3 - th3;                      \
    int cnt = (int)sp0 + (int)sp1 + (int)sp2 + (int)sp3;                       \
    cnt = wredi(cnt);                                                          \
    if (lane == 0) shc[wv] = cnt;                                              \
    __syncthreads();                                                           \
    if (wv == 0 && lane == 0) {                                                \
      int bc = ((((((shc[0] + shc[1]) + shc[2]) + shc[3]) + shc[4])            \
                 + shc[5]) + shc[6]) + shc[7];                                 \
      __hip_atomic_store(&g_cnt[(size_t)(T_) * PB + bid], (u32)bc + 1u,        \
                         __ATOMIC_RELAXED, __HIP_MEMORY_SCOPE_AGENT);          \
    }                                                                          \
    /* hidden under the sync round trip: bits pack + trace reductions */       \
    u32 nib = (u32)sp0 | ((u32)sp1 << 1) | ((u32)sp2 << 2) | ((u32)sp3 << 3);  \
    u32 word = nib << (4 * (tid & 7));                                         \
    word |= (u32)__shfl_xor((int)word, 1);                                     \
    word |= (u32)__shfl_xor((int)word, 2);                                     \
    word |= (u32)__shfl_xor((int)word, 4);                                     \
    if ((tid & 7) == 0) bits2[(size_t)(gtid >> 3) * TT + (T_)] = word;         \
    float msum = ((m0 + m1) + m2) + m3;                                        \
    float tsum = ((th0 + th1) + th2) + th3;                                    \
    msum = wredf(msum); tsum = wredf(tsum);                                    \
    if (lane == 0) {                                                           \
      wm[((size_t)(T_) * PB + bid) * NW + wv] = msum;                          \
      wt[((size_t)(T_) * PB + bid) * NW + wv] = tsum;                          \
    }                                                                          \
    if (wv == 0) {                                                             \
      if (bid == 0) {  /* master: collect 128 slots, publish one word */       \
        const u32* slots_ = g_cnt + (size_t)(T_) * PB;                         \
        u32 v0_, v1_; int gd_ = 0;                                             \
        while (1) {                                                            \
          v0_ = __hip_atomic_load(&slots_[lane],      __ATOMIC_RELAXED, __HIP_MEMORY_SCOPE_AGENT); \
          v1_ = __hip_atomic_load(&slots_[lane + 64], __ATOMIC_RELAXED, __HIP_MEMORY_SCOPE_AGENT); \
          if (__all(v0_ != 0u && v1_ != 0u)) break;                            \
          if (++gd_ > GUARD_MAX) break;                                        \
        }                                                                      \
        int ss_ = (int)(v0_ ? v0_ - 1u : 0u) + (int)(v1_ ? v1_ - 1u : 0u);     \
        ss_ = wredi(ss_);                                                      \
        if (lane == 0) {                                                       \
          __hip_atomic_store(&g_tot[(T_)], (u32)ss_ + 1u,                      \
                             __ATOMIC_RELAXED, __HIP_MEMORY_SCOPE_AGENT);      \
          s_tot = (u32)ss_;                                                    \
        }                                                                      \
      } else {         /* poll ONE uniform word (single line request/iter) */  \
        u32 v_; int gd_ = 0;                                                   \
        while (1) {                                                            \
          v_ = __hip_atomic_load(&g_tot[(T_)], __ATOMIC_RELAXED, __HIP_MEMORY_SCOPE_AGENT); \
          if (v_ != 0u) break;                                                 \
          if (++gd_ > GUARD_MAX) break;                                        \
          __builtin_amdgcn_s_sleep(1);                                         \
        }                                                                      \
        if (lane == 0) s_tot = (v_ ? v_ - 1u : 0u);                            \
      }                                                                        \
    }                                                                          \
    __syncthreads();                                                           \
    const float mean_ = (float)s_tot * 3.814697265625e-06f;                    \
    ema = __builtin_fmaf(0.99f, ema, 0.01f * mean_);                           \
    sc  = (tsv + 0.1f * fmaxf(ema - 0.01f, 0.0f)) + abv;                       \
  }

#define LOADC(X0,X1,X2,X3,X4,X5,X6,X7, c) {            \
    X0 = *(const float4*)(r0 + (c) * 8);               \
    X1 = *(const float4*)(r0 + (c) * 8 + 4);           \
    X2 = *(const float4*)(r1 + (c) * 8);               \
    X3 = *(const float4*)(r1 + (c) * 8 + 4);           \
    X4 = *(const float4*)(r2 + (c) * 8);               \
    X5 = *(const float4*)(r2 + (c) * 8 + 4);           \
    X6 = *(const float4*)(r3 + (c) * 8);               \
    X7 = *(const float4*)(r3 + (c) * 8 + 4); }

#define DOCHUNK(X0,X1,X2,X3,X4,X5,X6,X7, c) {                     \
    _Pragma("unroll")                                             \
    for (int k = 0; k < 8; ++k) {                                 \
      const float i0_ = (k < 4) ? f4c(X0, k) : f4c(X1, k);        \
      const float i1_ = (k < 4) ? f4c(X2, k) : f4c(X3, k);        \
      const float i2_ = (k < 4) ? f4c(X4, k) : f4c(X5, k);        \
      const float i3_ = (k < 4) ? f4c(X6, k) : f4c(X7, k);        \
      STEPSYNC(i0_, i1_, i2_, i3_, (c) * 8 + k);                  \
    } }

  float4 A0,A1,A2,A3,A4,A5,A6,A7;
  float4 B0,B1,B2,B3,B4,B5,B6,B7;

  LOADC(A0,A1,A2,A3,A4,A5,A6,A7, 0);
  for (int cc = 0; cc < 8; ++cc) {
    LOADC(B0,B1,B2,B3,B4,B5,B6,B7, 2 * cc + 1);         // prefetch odd chunk
    DOCHUNK(A0,A1,A2,A3,A4,A5,A6,A7, 2 * cc);
    if (cc < 7) LOADC(A0,A1,A2,A3,A4,A5,A6,A7, 2 * cc + 2);  // prefetch next even
    DOCHUNK(B0,B1,B2,B3,B4,B5,B6,B7, 2 * cc + 1);
  }
#undef DOCHUNK
#undef LOADC
#undef STEPSYNC

  // final adaptation partial + final ema
  float asum = ((a0 + a1) + a2) + a3;
  asum = wredf(asum);
  __syncthreads();
  if (lane == 0) shm[wv] = asum;
  __syncthreads();
  if (tid == 0) {
    float bs = 0.f;
    for (int w = 0; w < NW; ++w) bs += shm[w];
    wa[bid] = bs;
    if (bid == 0) out[OB + 256] = ema;   // ema after step 127
  }
}

// Deterministic fold of per-wave trace partials (1024 per step, fixed order).
__launch_bounds__(256)
__global__ void snn_finish(const float* __restrict__ wm, const float* __restrict__ wt,
                           const float* __restrict__ wa, float* __restrict__ out)
{
#pragma clang fp contract(off)
  const int tid = threadIdx.x;
  const float inv = 3.814697265625e-06f;   // 2^-18
  if (tid < 128) {
    float s = 0.f;
    for (int j = 0; j < PB * NW; ++j) s += wm[(size_t)tid * PB * NW + j];
    out[OB + tid] = s * inv;
  } else {
    const int t = tid - 128;
    float s = 0.f;
    for (int j = 0; j < PB * NW; ++j) s += wt[(size_t)t * PB * NW + j];
    out[OB + 128 + t] = s * inv;
  }
  if (tid == 0) {
    float s = 0.f;
    for (int b = 0; b < PB; ++b) s += wa[b];
    out[OB + 257] = s * inv;
  }
}

// bits2[word][t] -> float spikes [n][t]; uint4 reads + float4 writes, coalesced.
__global__ void snn_expand(const u32* __restrict__ bits2, float* __restrict__ outF)
{
  const int gtid = blockIdx.x * blockDim.x + threadIdx.x;
  const int wave = gtid >> 6, lane = gtid & 63;
  const int nwaves = (gridDim.x * blockDim.x) >> 6;
  const int nloc = lane >> 5;     // which neuron of the pair
  const int tq   = lane & 31;     // float4 chunk over t
  for (int pair = wave; pair < N_NEUR / 2; pair += nwaves) {
    const int n = 2 * pair + nloc;
    const uint4 w = *(const uint4*)(bits2 + (size_t)(n >> 5) * TT + 4 * tq);
    const int b = n & 31;
    float4 f;
    f.x = (float)((w.x >> b) & 1u);
    f.y = (float)((w.y >> b) & 1u);
    f.z = (float)((w.z >> b) & 1u);
    f.w = (float)((w.w >> b) & 1u);
    ((float4*)outF)[(size_t)n * (TT / 4) + tq] = f;
  }
}

extern "C" void kernel_launch(void* const* d_in, const int* in_sizes, int n_in,
                              void* d_out, int out_size, void* d_ws, size_t ws_size,
                              hipStream_t stream)
{
  const float* in  = (const float*)d_in[0];
  const float* tsp = (const float*)d_in[1];
  const float* abp = (const float*)d_in[2];
  float* out = (float*)d_out;
  unsigned char* ws = (unsigned char*)d_ws;

  if (ws_size < 5310000u) return;   // need ~5.1 MiB scratch

  u32*   bits2 = (u32*)(ws);                    // 4 MiB   [8192 words][128 t]
  float* wm    = (float*)(ws + 4194304);        // 512 KiB [128 t][128 b][8 w]
  float* wt    = (float*)(ws + 4718592);        // 512 KiB
  u32*   g_cnt = (u32*)(ws + 5242880);          // 64 KiB  [128 t][128 b] count+1
  u32*   g_tot = (u32*)(ws + 5308416);          // 512 B   [128 t] total+1
  float* wa    = (float*)(ws + 5308928);        // 512 B

  hipMemsetAsync(g_cnt, 0, 66048, stream);      // zero slots + totals (in-graph)

  snn_persist<<<dim3(PB), dim3(PT), 0, stream>>>(in, tsp, abp, out,
                                                 bits2, g_cnt, g_tot, wm, wt, wa);
  snn_finish<<<dim3(1), dim3(256), 0, stream>>>(wm, wt, wa, out);
  snn_expand<<<dim3(2048), dim3(256), 0, stream>>>(bits2, out);
}